// Round 7
// baseline (17.163 us; speedup 1.0000x reference)
//
#include <hip/hip_runtime.h>

// LengthRegulator fused single-kernel:
// reps = floor(dur + 0.5); out[b, m, :] = inputs[b, t, :] where
// cumsum[b][t] <= m < cumsum[b][t+1]; zeros for m >= output_lens[b].
// d_out = out flat [B*max_len*D] ++ output_lens [B] (as float).
//
// Block = one batch x 48 contiguous output frames, 384 threads (6 waves).
// Waves 0-3 redundantly shfl-scan the 512 durations (registers, 2 barriers)
// and scatter token ids into a 48-entry LDS frame->token map. Gather phase:
// each thread owns a fixed (frame_offset, d4) pair -> 12 independent,
// branch-free iterations. R7 A/B: plain stores (vs R6's nt-stores) --
// isolating whether __builtin_nontemporal_store was capping write BW.

#define BATCH 16
#define T_IN 512
#define DIM 384
#define D4 96            // float4 per row
#define FPB 48           // output frames per block
#define NT 384           // threads per block (6 waves)
#define ITERS (FPB * D4 / NT)  // 12

typedef float floatx4 __attribute__((ext_vector_type(4)));

__global__ __launch_bounds__(NT) void lr_fused_kernel(
    const float* __restrict__ dur,
    const floatx4* __restrict__ in4,
    floatx4* __restrict__ out4,
    float* __restrict__ lens_out,
    int max_len, int gx) {
    __shared__ int wsum[4];
    __shared__ int smap[FPB];

    // XCD-chunked swizzle: give XCD k the contiguous range [k*nwg/8, ...).
    const int nwg = gridDim.x;               // 16 * gx, divisible by 8
    const int id = blockIdx.x;
    const int wid = (id & 7) * (nwg >> 3) + (id >> 3);
    const int b = wid / gx;                  // batch
    const int fx = wid - b * gx;             // frame-chunk within batch

    const int tid = threadIdx.x;
    const int lane = tid & 63;
    const int w = tid >> 6;
    const int f0 = fx * FPB;

    if (tid < FPB) smap[tid] = -1;           // default: zero-fill frame

    // ---- scan: waves 0-3 hold 2 reps each, registers only ----
    int r0 = 0, s = 0, incl = 0;
    if (tid < 256) {
        float2 dp = *(const float2*)(dur + b * T_IN + 2 * tid);
        r0 = (int)floorf(dp.x + 0.5f);
        int r1 = (int)floorf(dp.y + 0.5f);
        s = r0 + r1;
        incl = s;
        #pragma unroll
        for (int off = 1; off < 64; off <<= 1) {
            int v = __shfl_up(incl, off);
            if (lane >= off) incl += v;
        }
        if (lane == 63) wsum[w] = incl;
    }
    __syncthreads();

    if (tid < 256) {
        int waveoff = 0;
        #pragma unroll
        for (int i = 0; i < 4; ++i)
            if (i < w) waveoff += wsum[i];
        const int c0 = waveoff + incl - s;   // cumsum before token 2*tid
        const int c1 = c0 + r0;              // before token 2*tid+1
        const int c2 = c0 + s;               // before token 2*tid+2
        const int f1 = f0 + FPB;
        int lo = max(c0, f0), hi = min(c1, f1);
        for (int j = lo; j < hi; ++j) smap[j - f0] = 2 * tid;
        lo = max(c1, f0); hi = min(c2, f1);
        for (int j = lo; j < hi; ++j) smap[j - f0] = 2 * tid + 1;
        if (fx == 0 && tid == 255) lens_out[b] = (float)c2;
    }
    __syncthreads();

    // ---- gather: 48 frames = 4608 float4, 12 per thread, branch-free ----
    const int f_off = tid / D4;              // 0..3 (computed once)
    const int d4 = tid - f_off * D4;         // 0..95
    const int per_b = max_len * D4;
    const floatx4* src_b = in4 + (size_t)b * T_IN * D4;
    floatx4* dst_b = out4 + (size_t)b * per_b;

    #pragma unroll
    for (int k = 0; k < ITERS; ++k) {
        const int lf = k * 4 + f_off;        // local frame 0..47
        const int frame = f0 + lf;
        const int t = smap[lf];
        const int ts = t < 0 ? 0 : t;        // clamp: load unconditional
        floatx4 val = src_b[ts * D4 + d4];
        if (t < 0) val = (floatx4)(0.f);
        if (frame < max_len)
            dst_b[frame * D4 + d4] = val;    // plain store (A/B vs nt)
    }
}

extern "C" void kernel_launch(void* const* d_in, const int* in_sizes, int n_in,
                              void* d_out, int out_size, void* d_ws, size_t ws_size,
                              hipStream_t stream) {
    const float* inputs = (const float*)d_in[0];
    const float* durations = (const float*)d_in[1];
    float* out = (float*)d_out;

    const int max_len = (out_size - BATCH) / (BATCH * DIM);
    float* lens_out = out + (size_t)BATCH * max_len * DIM;

    const int gx = (max_len + FPB - 1) / FPB;
    dim3 grid(gx * BATCH);
    lr_fused_kernel<<<grid, NT, 0, stream>>>(durations, (const floatx4*)inputs,
                                             (floatx4*)out, lens_out, max_len,
                                             gx);
}

// Round 8
// 16.284 us; speedup vs baseline: 1.0540x; 1.0540x over previous
//
#include <hip/hip_runtime.h>

// LengthRegulator fused single-kernel (best-known config = R5 + padded grid):
// reps = floor(dur + 0.5); out[b, m, :] = inputs[b, t, :] where
// cumsum[b][t] <= m < cumsum[b][t+1]; zeros for m >= output_lens[b].
// d_out = out flat [B*max_len*D] ++ output_lens [B] (as float).
//
// Each block: one batch x 24 contiguous output frames. Redundant per-block
// register shfl-scan of the 512 durations (2 barriers), scatter token ids
// into a 24-entry LDS frame->token map, then streaming float4 gather with
// non-temporal stores (A/B-verified +0.6us vs plain). XCD-chunked swizzle.
// Grid padded to a multiple of 256 blocks -> exactly 6 blocks/CU, removing
// the ~4% finishing-tail imbalance of 5.75 blocks/CU.

#define BATCH 16
#define T_IN 512
#define DIM 384
#define D4 96            // float4 per row
#define FPB 24           // output frames per block
#define VPB (FPB * D4)   // 2304 float4 vectors per block
#define NT 256           // threads per block (4 waves)

typedef float floatx4 __attribute__((ext_vector_type(4)));

__global__ __launch_bounds__(NT) void lr_fused_kernel(
    const float* __restrict__ dur,
    const floatx4* __restrict__ in4,
    floatx4* __restrict__ out4,
    float* __restrict__ lens_out,
    int max_len, int gx) {
    __shared__ int wsum[NT / 64];
    __shared__ int smap[FPB];

    // XCD-chunked swizzle: HW round-robins dispatch id % 8 across XCDs, so
    // give XCD k the contiguous work range [k*nwg/8, (k+1)*nwg/8).
    const int nwg = gridDim.x;               // 16 * gx, divisible by 8
    const int id = blockIdx.x;
    const int wid = (id & 7) * (nwg >> 3) + (id >> 3);
    const int b = wid / gx;                  // batch
    const int fx = wid - b * gx;             // frame-chunk within batch

    const int tid = threadIdx.x;
    const int lane = tid & 63;
    const int w = tid >> 6;

    // ---- scan: 512 reps, 2 per thread, registers only ----
    float2 dp = *(const float2*)(dur + b * T_IN + 2 * tid);
    int r0 = (int)floorf(dp.x + 0.5f);
    int r1 = (int)floorf(dp.y + 0.5f);
    int s = r0 + r1;
    int incl = s;
    #pragma unroll
    for (int off = 1; off < 64; off <<= 1) {
        int v = __shfl_up(incl, off);
        if (lane >= off) incl += v;
    }
    if (lane == 63) wsum[w] = incl;
    if (tid < FPB) smap[tid] = -1;   // default: zero-fill frame
    __syncthreads();

    int waveoff = 0;
    #pragma unroll
    for (int i = 0; i < NT / 64; ++i)
        if (i < w) waveoff += wsum[i];

    const int c0 = waveoff + incl - s;  // cumsum before token 2*tid
    const int c1 = c0 + r0;             // before token 2*tid+1
    const int c2 = c0 + s;              // before token 2*tid+2

    const int f0 = fx * FPB;
    const int f1 = f0 + FPB;
    // scatter: token 2*tid covers frames [c0, c1), token 2*tid+1 [c1, c2)
    {
        int lo = max(c0, f0), hi = min(c1, f1);
        for (int j = lo; j < hi; ++j) smap[j - f0] = 2 * tid;
        lo = max(c1, f0); hi = min(c2, f1);
        for (int j = lo; j < hi; ++j) smap[j - f0] = 2 * tid + 1;
    }
    if (fx == 0 && tid == NT - 1) lens_out[b] = (float)c2;
    __syncthreads();

    // ---- gather: 24 frames = 2304 float4, 9 per thread ----
    const int per_b = max_len * D4;
    const int v0 = fx * VPB;
    const floatx4* src_b = in4 + (size_t)b * T_IN * D4;
    floatx4* dst_b = out4 + (size_t)b * per_b;

    #pragma unroll
    for (int k = 0; k < VPB / NT; ++k) {
        int lv = tid + k * NT;          // 0..2303 within block chunk
        int v = v0 + lv;
        if (v >= per_b) break;          // padded chunks exit here
        int ml = lv / D4;               // local frame 0..23 (const divisor)
        int d4 = lv - ml * D4;
        int t = smap[ml];
        floatx4 val = (floatx4)(0.f);
        if (t >= 0) val = src_b[t * D4 + d4];
        __builtin_nontemporal_store(val, &dst_b[v]);
    }
}

extern "C" void kernel_launch(void* const* d_in, const int* in_sizes, int n_in,
                              void* d_out, int out_size, void* d_ws, size_t ws_size,
                              hipStream_t stream) {
    const float* inputs = (const float*)d_in[0];
    const float* durations = (const float*)d_in[1];
    float* out = (float*)d_out;

    const int max_len = (out_size - BATCH) / (BATCH * DIM);
    float* lens_out = out + (size_t)BATCH * max_len * DIM;

    // Pad chunks/batch to a multiple of 16 so total blocks is a multiple of
    // 256 (exactly 6 blocks per CU at max_len ~= 2192).
    int gx = (max_len + FPB - 1) / FPB;
    gx = (gx + 15) & ~15;
    dim3 grid(gx * BATCH);
    lr_fused_kernel<<<grid, NT, 0, stream>>>(durations, (const floatx4*)inputs,
                                             (floatx4*)out, lens_out, max_len,
                                             gx);
}